// Round 1
// 136.715 us; speedup vs baseline: 1.1141x; 1.1141x over previous
//
#include <hip/hip_runtime.h>

// LocalConnectivity: out[i][j] = sum_{1<=|dx|+|dy|<=5} w_{|dx|+|dy|} * s[(i+dx)&4095][(j+dy)&4095]
// w_d = exp(-d/2) = r^d  =>  separable per diagonal: w_{|dx|+|dy|} = r^|dx| * r^|dy|
// out[i][j] = sum_{dx=-5..5} r^|dx| * H_{5-|dx|}[i+dx][j] - s[i][j]
// H_k[t][j] = sum_{|dy|<=k} r^|dy| s[t][j+dy]  (incremental: 5 add + 5 fma)
//
// R7 (prev session): pure-TLP 4x8 patch, 14 streamed rows, ~68 us/dispatch.
// R8 (this round): counters showed FETCH=165MB vs 67MB ideal (2.5x halo re-fetch
// across non-coherent XCD L2s) + write stream thrashing the 4MiB/XCD L2.
//   (a) XCD-band swizzle: bid&7 -> XCD, each XCD owns a contiguous band of 128
//       y-chunks, so all ~3.5 consumers of an input row are co-resident on ONE
//       L2 -> row fetched from HBM ~once.
//   (b) nontemporal stores: evict-first hint keeps the read halo resident.

#define GH     4096
#define GMASK  4095
#define RCHUNK 4           // output rows per thread
#define NR     (RCHUNK + 10)   // 14 input rows streamed

typedef float f4 __attribute__((ext_vector_type(4), aligned(16)));

__global__ __launch_bounds__(256)
void diamond_stencil(const float* __restrict__ s, const float* __restrict__ w,
                     float* __restrict__ out)
{
    const int tid = threadIdx.x;

    // XCD-band swizzle: dispatch assigns consecutive blockIdx round-robin over
    // 8 XCDs. Map bid so XCD k gets y-chunks [k*128, (k+1)*128), both column
    // strips, consecutive idx -> neighboring y (halo sharers co-resident in L2).
    const int bid = blockIdx.x;            // 0..2047
    const int xcd = bid & 7;
    const int idx = bid >> 3;              // 0..255 within this XCD
    const int bx  = idx & 1;               // column strip
    const int by  = xcd * 128 + (idx >> 1);// y-chunk, contiguous band per XCD

    const int j0  = bx * 2048 + tid * 8;   // 8 columns per thread, 32B-aligned
    const int t0  = by * RCHUNK;           // 4 output rows per thread

    // wrapped column bases (all float4 bases stay 16B-aligned; wrap only at strip edges)
    const int cL  = (j0 - 5) & GMASK;      // scalar left halo
    const int cm4 = (j0 - 4) & GMASK;
    const int cp8 = (j0 + 8) & GMASK;
    const int cR  = (j0 + 12) & GMASK;     // scalar right halo

    float wgt[6];
    wgt[0] = 1.0f;
#pragma unroll
    for (int d = 1; d <= 5; ++d) wgt[d] = w[d - 1];   // exp(-d/2)

    float acc[RCHUNK][8];
#pragma unroll
    for (int a = 0; a < RCHUNK; ++a)
#pragma unroll
        for (int c = 0; c < 8; ++c) acc[a][c] = 0.0f;

#pragma unroll
    for (int r = 0; r < NR; ++r) {
        const float* row = s + ((size_t)((t0 - 5 + r) & GMASK) << 12);

        // 18 floats: cols j0-5 .. j0+12 (6 independent loads, hoistable)
        float v[18];
        v[0] = row[cL];
        const float4 A = *(const float4*)(row + cm4);
        const float4 B = *(const float4*)(row + j0);
        const float4 C = *(const float4*)(row + j0 + 4);
        const float4 D = *(const float4*)(row + cp8);
        v[17] = row[cR];
        v[1]  = A.x; v[2]  = A.y; v[3]  = A.z; v[4]  = A.w;
        v[5]  = B.x; v[6]  = B.y; v[7]  = B.z; v[8]  = B.w;
        v[9]  = C.x; v[10] = C.y; v[11] = C.z; v[12] = C.w;
        v[13] = D.x; v[14] = D.y; v[15] = D.z; v[16] = D.w;

#pragma unroll
        for (int c = 0; c < 8; ++c) {
            const float ctr = v[5 + c];
            float Hs[6];
            Hs[0] = ctr;
#pragma unroll
            for (int k = 1; k <= 5; ++k)
                Hs[k] = Hs[k - 1] + wgt[k] * (v[5 + c - k] + v[5 + c + k]);

            // input row t = t0-5+r contributes to output row o = t0+a iff |r-5-a| <= 5
#pragma unroll
            for (int a = 0; a < RCHUNK; ++a) {
                const int d = r - 5 - a;               // compile-time
                if (d < -5 || d > 5) continue;
                if (d == 0)
                    acc[a][c] += Hs[5] - ctr;          // center excluded
                else {
                    const int ad = d < 0 ? -d : d;
                    acc[a][c] += wgt[ad] * Hs[5 - ad];
                }
            }
        }
    }

    // store 4 rows x 8 cols, nontemporal (evict-first: don't thrash L2 read set)
#pragma unroll
    for (int a = 0; a < RCHUNK; ++a) {
        float* op = out + ((size_t)(t0 + a) << 12) + j0;
        f4 r0, r1;
        r0.x = acc[a][0]; r0.y = acc[a][1]; r0.z = acc[a][2]; r0.w = acc[a][3];
        r1.x = acc[a][4]; r1.y = acc[a][5]; r1.z = acc[a][6]; r1.w = acc[a][7];
        __builtin_nontemporal_store(r0, (f4*)op);
        __builtin_nontemporal_store(r1, (f4*)(op + 4));
    }
}

extern "C" void kernel_launch(void* const* d_in, const int* in_sizes, int n_in,
                              void* d_out, int out_size, void* d_ws, size_t ws_size,
                              hipStream_t stream)
{
    const float* s = (const float*)d_in[0];   // grid_spikes [4096*4096] f32
    const float* w = (const float*)d_in[1];   // distance_weights [5] f32
    float* out = (float*)d_out;               // [4096*4096] f32

    // 2048 blocks (2 col strips x 1024 row-chunks), XCD-band swizzled in-kernel
    dim3 grid(2048);
    dim3 block(256);
    diamond_stencil<<<grid, block, 0, stream>>>(s, w, out);
}